// Round 3
// baseline (568.049 us; speedup 1.0000x reference)
//
#include <hip/hip_runtime.h>

// CosineSelfAttention  B=4, S=8192, HID=768, NH=12, HD=64, EPS=1e-5
// Round 9: widen gemm_qkv block to 128 rows x 384 cols (head-pair x {Q,K,V}).
// 8 waves of 64x96 (acc 4x6): ds_read:MFMA ratio 0.67 -> 0.42, one 64KB
// staging pass feeds 384 MFMAs (was 40KB->192). Epilogue sequences qn scatter
// and K^T/V^T transpose through the same LDS region (78KB total). Downstream
// kernels and all buffer layouts unchanged from round 8.

typedef unsigned short u16;
typedef unsigned int u32;

#define B_ 4
#define S_ 8192
#define HID_ 768
#define NH_ 12
#define HD_ 64
#define EPS_ 1e-5f

typedef __attribute__((ext_vector_type(8))) short bf16x8;
typedef __attribute__((ext_vector_type(4))) float f32x4;

__device__ __forceinline__ float bf2f(unsigned int u) {
    u <<= 16;
    return __builtin_bit_cast(float, u);
}
__device__ __forceinline__ u16 f2bf(float f) {
    u32 u = __builtin_bit_cast(u32, f);
    u = u + 0x7fffu + ((u >> 16) & 1u);   // round-to-nearest-even
    return (u16)(u >> 16);
}

#define ASYNC16(gptr, lptr)                                                        \
    __builtin_amdgcn_global_load_lds(                                              \
        (const __attribute__((address_space(1))) void*)(gptr),                     \
        (__attribute__((address_space(3))) void*)(lptr), 16, 0, 0)

// ---------------------------------------------------------------------------
// Kernel 0: dtype sniff (1 = fp32, 0 = bf16); also zero msumws.
// ---------------------------------------------------------------------------
__global__ void sniff_k(const void* __restrict__ X, u32* __restrict__ flag,
                        float* __restrict__ msumws)
{
    __shared__ int bad;
    if (threadIdx.x == 0) bad = 0;
    if (threadIdx.x < 4) msumws[threadIdx.x] = 0.f;
    __syncthreads();
    const u16* p = (const u16*)X;
    int loc = 0;
    for (int i = threadIdx.x; i < 8192; i += 256) {
        const u32 u = p[2 * i];
        const u32 e = (u >> 7) & 0xFFu;
        if (e >= 0xF8u) loc = 1;
    }
    if (loc) bad = 1;
    __syncthreads();
    if (threadIdx.x == 0) *flag = (u32)bad;
}

// ---------------------------------------------------------------------------
// Kernel 0b: convert X | Wq,Wk,Wv | mask | biases -> bf16 buffers.
// ---------------------------------------------------------------------------
__global__ __launch_bounds__(256) void conv_k(
    const void* __restrict__ X,
    const void* __restrict__ Wq, const void* __restrict__ Wk, const void* __restrict__ Wv,
    const void* __restrict__ bq, const void* __restrict__ bk, const void* __restrict__ bv,
    const void* __restrict__ mask,
    const u32* __restrict__ flagp,
    u16* __restrict__ Xb, u16* __restrict__ Wb, u16* __restrict__ Mb, u16* __restrict__ Bb)
{
    const int id = blockIdx.x;
    const void* src;
    u16* dst;
    int e;
    if (id < 12288) {                       // X
        src = X; dst = Xb; e = id * 2048 + threadIdx.x * 8;
    } else if (id < 13152) {                // W: 3 x 589824
        const int i = id - 12288;
        const int mat = i / 288;
        e = (i % 288) * 2048 + threadIdx.x * 8;
        src = (mat == 0) ? Wq : (mat == 1) ? Wk : Wv;
        dst = Wb + (size_t)mat * 589824;
    } else if (id < 13168) {                // mask: 32768
        const int i = id - 13152;
        src = mask; dst = Mb; e = i * 2048 + threadIdx.x * 8;
    } else {                                // biases: 3 x 768
        const int i = id - 13168;
        const int e0 = i * 2048 + threadIdx.x * 8;
        if (e0 >= 2304) return;
        const int mat = e0 / 768;
        src = (mat == 0) ? bq : (mat == 1) ? bk : bv;
        dst = Bb + mat * 768;
        e = e0 - mat * 768;
    }
    if (*flagp) {
        const float* s = (const float*)src + e;
        const float4 lo = *(const float4*)(s);
        const float4 hi = *(const float4*)(s + 4);
        uint4 o;
        o.x = (u32)f2bf(lo.x) | ((u32)f2bf(lo.y) << 16);
        o.y = (u32)f2bf(lo.z) | ((u32)f2bf(lo.w) << 16);
        o.z = (u32)f2bf(hi.x) | ((u32)f2bf(hi.y) << 16);
        o.w = (u32)f2bf(hi.z) | ((u32)f2bf(hi.w) << 16);
        *(uint4*)(dst + e) = o;
    } else {
        *(uint4*)(dst + e) = *(const uint4*)((const u16*)src + e);
    }
}

// ---------------------------------------------------------------------------
// Kernel 1: fused QKV GEMM, 128 rows x head-pair (2 heads) x {Q,K,V}.
// Output cols c in [0,384): tile t = c/64 -> t0,t1 = Q h0,h1; t2,t3 = K;
// t4,t5 = V. 512 threads = 8 waves, wm = wid>>2 (64-row half), wn = wid&3
// (96-col quarter). acc[4][6]. Staging: A[128][64] + 6x B[64][64] = 64KB.
// Epilogue: ss -> invn (mask/cosine) -> scale in place -> qn scatter+store
// -> K^T/V^T scatter -> colsums, kv MFMA partials (deterministic).
// ---------------------------------------------------------------------------
__global__ __launch_bounds__(512, 2) void gemm_qkv_k(
    const u16* __restrict__ Xb, const u16* __restrict__ Wb,
    const u16* __restrict__ Bb, const u16* __restrict__ Mb,
    u16* __restrict__ qn, float* __restrict__ kvpart,
    float* __restrict__ kspart, float* __restrict__ vspart,
    float* __restrict__ msumws)
{
    __shared__ u16 smem[32768];            // 64KB: A|B staging; then qn / K^T,V^T
    __shared__ float ssbuf[4][4][128];     // [tile Qh0,Qh1,Kh0,Kh1][wn][row]
    __shared__ float invn[4][128];         // mf/(||.||+eps) per tile,row
    __shared__ float colsum[2][2][128];    // [K/V][wm][col in head-pair]

    const int tid  = threadIdx.x;
    const int lane = tid & 63;
    const int wid  = tid >> 6;
    const int wm   = wid >> 2;             // 0..1  (64-row half)
    const int wn   = wid & 3;              // 0..3  (96-col quarter)

    const int bid   = blockIdx.x;
    const int work  = (bid & 7) * 192 + (bid >> 3);   // XCD-contiguous
    const int row_t = work / 6;            // 0..255
    const int hp    = work % 6;            // head pair
    const int b     = row_t >> 6;
    const int rt_b  = row_t & 63;
    const int arow0 = row_t * 128;
    const int bh0   = b * NH_ + hp * 2;

    // ---- staging map: 64 chunks (A:16, B:48), 8 per wave
    const u16* src8[8];
    int loff8[8];
#pragma unroll
    for (int t = 0; t < 8; ++t) {
        const int cg = wid * 8 + t;
        const u16* base;
        int row;
        if (cg < 16) {
            row  = cg * 8 + (lane >> 3);
            base = Xb + (size_t)(arow0 + row) * HID_;
        } else {
            const int bi   = cg - 16;
            const int tile = bi >> 3;              // 0..5
            const int mat  = tile >> 1;
            const int h2   = tile & 1;
            row = (bi & 7) * 8 + (lane >> 3);      // col-in-tile (W row)
            base = Wb + (size_t)mat * 589824 +
                   (size_t)(hp * 128 + h2 * 64 + row) * HID_;
        }
        const int gseg = (lane & 7) ^ (row & 7);
        src8[t]  = base + gseg * 8;
        loff8[t] = cg * 512;
    }

    f32x4 acc[4][6];
#pragma unroll
    for (int i = 0; i < 4; ++i)
#pragma unroll
        for (int j = 0; j < 6; ++j) acc[i][j] = (f32x4){0.f, 0.f, 0.f, 0.f};

    for (int k0 = 0; k0 < HID_; k0 += 64) {
#pragma unroll
        for (int t = 0; t < 8; ++t)
            ASYNC16(src8[t] + k0, smem + loff8[t]);
        __syncthreads();
#pragma unroll
        for (int ks = 0; ks < 2; ++ks) {
            const int phys = ((ks * 4 + (lane >> 4)) ^ (lane & 7)) * 8;
            bf16x8 af[4];
#pragma unroll
            for (int i = 0; i < 4; ++i)
                af[i] = *(const bf16x8*)(smem + (wm * 64 + i * 16 + (lane & 15)) * 64 + phys);
#pragma unroll
            for (int j = 0; j < 6; ++j) {
                const int cb = wn * 96 + j * 16;
                const int tj = cb >> 6, tc = cb & 63;
                const bf16x8 bf = *(const bf16x8*)(smem + 8192 + tj * 4096 +
                                   (tc + (lane & 15)) * 64 + phys);
#pragma unroll
                for (int i = 0; i < 4; ++i)
                    acc[i][j] = __builtin_amdgcn_mfma_f32_16x16x32_bf16(af[i], bf, acc[i][j], 0, 0, 0);
            }
        }
        __syncthreads();
    }

    // ---- bias
#pragma unroll
    for (int j = 0; j < 6; ++j) {
        const int cb = wn * 96 + j * 16;
        const int tj = cb >> 6, tc = cb & 63;
        const int mat = tj >> 1, h2 = tj & 1;
        const float bs = bf2f(Bb[mat * 768 + hp * 128 + h2 * 64 + tc + (lane & 15)]);
#pragma unroll
        for (int i = 0; i < 4; ++i)
#pragma unroll
            for (int r = 0; r < 4; ++r) acc[i][j][r] += bs;
    }

    // ---- row sum-of-squares per (tile Qh0,Qh1,Kh0,Kh1)
#pragma unroll
    for (int i = 0; i < 4; ++i)
#pragma unroll
        for (int r = 0; r < 4; ++r) {
            float p0 = 0.f, p1 = 0.f, p2 = 0.f, p3 = 0.f;
#pragma unroll
            for (int j = 0; j < 6; ++j) {
                const int tj = (wn * 96 + j * 16) >> 6;
                const float v = acc[i][j][r];
                if (tj == 0) p0 += v * v;
                else if (tj == 1) p1 += v * v;
                else if (tj == 2) p2 += v * v;
                else if (tj == 3) p3 += v * v;
            }
#pragma unroll
            for (int off = 1; off < 16; off <<= 1) {
                p0 += __shfl_xor(p0, off, 64);
                p1 += __shfl_xor(p1, off, 64);
                p2 += __shfl_xor(p2, off, 64);
                p3 += __shfl_xor(p3, off, 64);
            }
            if ((lane & 15) == 0) {
                const int row = wm * 64 + i * 16 + (lane >> 4) * 4 + r;
                ssbuf[0][wn][row] = p0;
                ssbuf[1][wn][row] = p1;
                ssbuf[2][wn][row] = p2;
                ssbuf[3][wn][row] = p3;
            }
        }
    __syncthreads();

    // ---- invn = mask / (sqrt(ss) + eps)
    {
        const int t4 = tid >> 7, row = tid & 127;
        const float ss = ssbuf[t4][0][row] + ssbuf[t4][1][row] +
                         ssbuf[t4][2][row] + ssbuf[t4][3][row];
        const float mk = bf2f(Mb[arow0 + row]);
        const float mf = (mk == 0.f) ? 1.f : 0.f;
        invn[t4][row] = mf / (sqrtf(ss) + EPS_);
    }
    __syncthreads();

    // ---- scale Q,K acc in place
#pragma unroll
    for (int i = 0; i < 4; ++i)
#pragma unroll
        for (int r = 0; r < 4; ++r) {
            const int row = wm * 64 + i * 16 + (lane >> 4) * 4 + r;
            const float s0 = invn[0][row], s1 = invn[1][row];
            const float s2 = invn[2][row], s3 = invn[3][row];
#pragma unroll
            for (int j = 0; j < 6; ++j) {
                const int tj = (wn * 96 + j * 16) >> 6;
                if (tj == 0) acc[i][j][r] *= s0;
                else if (tj == 1) acc[i][j][r] *= s1;
                else if (tj == 2) acc[i][j][r] *= s2;
                else if (tj == 3) acc[i][j][r] *= s3;
            }
        }

    // ---- qn scatter into smem [128][136] (pad 8)
#pragma unroll
    for (int i = 0; i < 4; ++i)
#pragma unroll
        for (int r = 0; r < 4; ++r) {
            const int row = wm * 64 + i * 16 + (lane >> 4) * 4 + r;
#pragma unroll
            for (int j = 0; j < 6; ++j) {
                const int cb = wn * 96 + j * 16;
                const int tj = cb >> 6;
                if (tj <= 1) {
                    const int c = (tj << 6) + (cb & 63) + (lane & 15);
                    smem[row * 136 + c] = f2bf(acc[i][j][r]);
                }
            }
        }

    // ---- colsum partials (K scaled, V raw) -> colsum LDS
#pragma unroll
    for (int j = 0; j < 6; ++j) {
        const int cb = wn * 96 + j * 16;
        const int tj = cb >> 6;
        if (tj >= 2) {
            const int m = (tj >> 1) - 1;      // 0=K, 1=V
            const int h2 = tj & 1;
            float s = 0.f;
#pragma unroll
            for (int i = 0; i < 4; ++i)
#pragma unroll
                for (int r = 0; r < 4; ++r) s += acc[i][j][r];
            s += __shfl_xor(s, 16, 64);
            s += __shfl_xor(s, 32, 64);
            if (lane < 16) colsum[m][wm][(h2 << 6) + (cb & 63) + lane] = s;
        }
    }
    __syncthreads();

    // ---- qn store: 128 rows x 128 cols bf16, coalesced
    {
        const int r = tid >> 2, cb2 = (tid & 3) * 32;
        u16* dq = qn + (size_t)(arow0 + r) * HID_ + hp * 128 + cb2;
        *(uint4*)(dq)      = *(const uint4*)(smem + r * 136 + cb2);
        *(uint4*)(dq + 8)  = *(const uint4*)(smem + r * 136 + cb2 + 8);
        *(uint4*)(dq + 16) = *(const uint4*)(smem + r * 136 + cb2 + 16);
        *(uint4*)(dq + 24) = *(const uint4*)(smem + r * 136 + cb2 + 24);
    }
    __syncthreads();

    // ---- K^T/V^T scatter: [KT h0 | KT h1 | VT h0 | VT h1], each [64 d][128 s]
#pragma unroll
    for (int i = 0; i < 4; ++i)
#pragma unroll
        for (int r = 0; r < 4; ++r) {
            const int row = wm * 64 + i * 16 + (lane >> 4) * 4 + r;
#pragma unroll
            for (int j = 0; j < 6; ++j) {
                const int cb = wn * 96 + j * 16;
                const int tj = cb >> 6;
                if (tj >= 2) {
                    const int h2 = tj & 1;
                    const int d  = (cb & 63) + (lane & 15);
                    const int base = ((tj >= 4) ? 16384 : 0) + h2 * 8192;
                    smem[base + d * 128 + ((((row >> 3) ^ (d & 7)) << 3) | (row & 7))] =
                        f2bf(acc[i][j][r]);
                }
            }
        }
    __syncthreads();

    // ---- kspart/vspart store
    if (tid < 256) {
        const int m = tid >> 7, c = tid & 127;
        (m ? vspart : kspart)[row_t * 768 + hp * 128 + c] =
            colsum[m][0][c] + colsum[m][1][c];
    }

    // ---- msum (hp==0 blocks only)
    if (hp == 0 && tid >= 256 && tid < 384) {
        float c = (bf2f(Mb[arow0 + (tid - 256)]) == 0.f) ? 1.f : 0.f;
#pragma unroll
        for (int off = 32; off > 0; off >>= 1) c += __shfl_down(c, off, 64);
        if (lane == 0) atomicAdd(&msumws[b], c);
    }

    // ---- kv partial: head hd = wid>>2, D row-block = wid&3
    {
        const int hd = wid >> 2;
        const int D  = wid & 3;
        const u16* lK = smem + hd * 8192;
        const u16* lV = smem + 16384 + hd * 8192;
        f32x4 akv[4];
#pragma unroll
        for (int E = 0; E < 4; ++E) akv[E] = (f32x4){0.f, 0.f, 0.f, 0.f};
#pragma unroll
        for (int ks = 0; ks < 4; ++ks) {
            const int physs = ((ks * 4 + (lane >> 4)) ^ (lane & 7)) * 8;
            const bf16x8 ak = *(const bf16x8*)(lK + (D * 16 + (lane & 15)) * 128 + physs);
#pragma unroll
            for (int E = 0; E < 4; ++E) {
                const bf16x8 bv = *(const bf16x8*)(lV + (E * 16 + (lane & 15)) * 128 + physs);
                akv[E] = __builtin_amdgcn_mfma_f32_16x16x32_bf16(ak, bv, akv[E], 0, 0, 0);
            }
        }
        float* dst = kvpart + ((size_t)(bh0 + hd) * 64 + rt_b) * 4096;
#pragma unroll
        for (int E = 0; E < 4; ++E)
#pragma unroll
            for (int r = 0; r < 4; ++r)
                dst[(D * 16 + (lane >> 4) * 4 + r) * 64 + E * 16 + (lane & 15)] = akv[E][r];
    }
}

// ---------------------------------------------------------------------------
// Kernel 2: reduce kv partials (x<48) + ks/vs partials (x==48). grid (49,4).
// ---------------------------------------------------------------------------
__global__ __launch_bounds__(256) void kvred_k(
    const float* __restrict__ kvpart, float* __restrict__ kvredw,
    const float* __restrict__ kspart, const float* __restrict__ vspart,
    float* __restrict__ ksred, float* __restrict__ vsred)
{
    if (blockIdx.x < 48) {
        const int bhi  = blockIdx.x;
        const int base = blockIdx.y * 1024 + threadIdx.x * 4;
        const float* p = kvpart + (size_t)bhi * 64 * 4096 + base;
        f32x4 s = (f32x4){0.f, 0.f, 0.f, 0.f};
        for (int rt = 0; rt < 64; ++rt)
            s += *(const f32x4*)(p + (size_t)rt * 4096);
        *(f32x4*)(kvredw + (size_t)bhi * 4096 + base) = s;
    } else {
#pragma unroll
        for (int i = 0; i < 6; ++i) {
            const int idx = blockIdx.y * 1536 + i * 256 + threadIdx.x;   // 0..6143
            const int m = idx / 3072;
            const int rest = idx % 3072;
            const int bb = rest / 768;
            const int c  = rest % 768;
            const float* src = m ? vspart : kspart;
            float s = 0.f;
            for (int rt = 0; rt < 64; ++rt) s += src[(bb * 64 + rt) * 768 + c];
            (m ? vsred : ksred)[bb * 768 + c] = s;
        }
    }
}

// ---------------------------------------------------------------------------
// Kernel 3: out = (qn @ (kvH+kvL) + vsum) / (eps + msum + qn.ksum).
// ---------------------------------------------------------------------------
__global__ __launch_bounds__(256) void out_k(
    const u16* __restrict__ qn, const float* __restrict__ kvredw,
    const float* __restrict__ ksred, const float* __restrict__ vsred,
    const float* __restrict__ msumws, float* __restrict__ out)
{
    __shared__ u16 qs[128 * 128];          // [row][128] seg-swz by row&15
    __shared__ u16 ekvH[2 * 64 * 64];      // [hd][e][d swz]
    __shared__ u16 ekvL[2 * 64 * 64];
    __shared__ float ksl[128];
    __shared__ float vsl[128];
    __shared__ float dnl[256];

    const int tid  = threadIdx.x;
    const int lane = tid & 63;
    const int wid  = tid >> 6;
    const int wm   = wid >> 1, wn = wid & 1;

    const int bid   = blockIdx.x;
    const int row_t = bid / 6;
    const int ncol  = bid % 6;
    const int b     = row_t >> 6;
    const int arow0 = row_t * 128;
    const int bh0   = b * NH_ + ncol * 2;

    // stage qn tile (32 chunks, 8 per wave), seg pre-swizzled by row&15
#pragma unroll
    for (int t = 0; t < 8; ++t) {
        const int c   = wid * 8 + t;
        const int row = c * 4 + (lane >> 4);
        const int gseg = (lane & 15) ^ (row & 15);
        ASYNC16(qn + (size_t)(arow0 + row) * HID_ + ncol * 128 + gseg * 8,
                qs + c * 512);
    }

    // preload kv hi/lo split + ksum/vsum
    for (int it = 0; it < 32; ++it) {
        const int idx = it * 256 + tid;          // 8192 = 2 heads x 64d x 64e
        const int hd = idx >> 12;
        const int de = idx & 4095;
        const int d = de >> 6, e = de & 63;
        const float v = kvredw[(size_t)(bh0 + hd) * 4096 + de];
        const u16 hi = f2bf(v);
        const float rem = v - bf2f(hi);
        const int adr = hd * 4096 + e * 64 + ((((d >> 3) ^ (e & 7)) << 3) | (d & 7));
        ekvH[adr] = hi;
        ekvL[adr] = f2bf(rem);
    }
    if (tid < 128) {
        const int hd = tid >> 6, c = tid & 63;
        const int col = (ncol * 2 + hd) * 64 + c;
        ksl[tid] = ksred[b * 768 + col];
        vsl[tid] = vsred[b * 768 + col];
    }
    __syncthreads();

    // den = eps + msum + qn . ksum
    {
        const int row = tid & 127, hd2 = tid >> 7;
        float den = EPS_ + msumws[b];
#pragma unroll
        for (int c8 = 0; c8 < 8; ++c8) {
            const int colbase = hd2 * 64 + c8 * 8;
            const int phys = ((colbase >> 3) ^ (row & 15)) << 3;
            const bf16x8 qv = *(const bf16x8*)(qs + row * 128 + phys);
#pragma unroll
            for (int m = 0; m < 8; ++m)
                den += bf2f((u16)qv[m]) * ksl[colbase + m];
        }
        dnl[hd2 * 128 + row] = 1.f / den;
    }
    __syncthreads();

    // MFMA matvec: o = qn @ (kvH + kvL)   (head = wn)
    f32x4 o4[4][4];
#pragma unroll
    for (int i = 0; i < 4; ++i)
#pragma unroll
        for (int j = 0; j < 4; ++j) o4[i][j] = (f32x4){0.f, 0.f, 0.f, 0.f};
#pragma unroll
    for (int ks = 0; ks < 2; ++ks) {
        bf16x8 aq[4], bkH[4], bkL[4];
#pragma unroll
        for (int i = 0; i < 4; ++i) {
            const int row = wm * 64 + i * 16 + (lane & 15);
            const int colbase = wn * 64 + ks * 32 + (lane >> 4) * 8;
            const int phys = ((colbase >> 3) ^ (row & 15)) << 3;
            aq[i] = *(const bf16x8*)(qs + row * 128 + phys);
        }
#pragma unroll
        for (int j = 0; j < 4; ++j) {
            const int e = j * 16 + (lane & 15);
            const int physd = (((ks * 4 + (lane >> 4)) ^ (e & 7)) << 3);
            bkH[j] = *(const bf16x8*)(ekvH + wn * 4096 + e * 64 + physd);
            bkL[j] = *(const bf16x8*)(ekvL + wn * 4096 + e * 64 + physd);
        }
#pragma unroll
        for (int i = 0; i < 4; ++i)
#pragma unroll
            for (int j = 0; j < 4; ++j) {
                o4[i][j] = __builtin_amdgcn_mfma_f32_16x16x32_bf16(aq[i], bkH[j], o4[i][j], 0, 0, 0);
                o4[i][j] = __builtin_amdgcn_mfma_f32_16x16x32_bf16(aq[i], bkL[j], o4[i][j], 0, 0, 0);
            }
    }

    // + vsum, x 1/den, store fp32
#pragma unroll
    for (int i = 0; i < 4; ++i) {
#pragma unroll
        for (int r = 0; r < 4; ++r) {
            const int row = wm * 64 + i * 16 + (lane >> 4) * 4 + r;
            const float inv = dnl[wn * 128 + row];
            float* op = out + (size_t)(arow0 + row) * HID_ + ncol * 128 + wn * 64;
#pragma unroll
            for (int j = 0; j < 4; ++j) {
                const int e = j * 16 + (lane & 15);
                op[e] = (o4[i][j][r] + vsl[wn * 64 + e]) * inv;
            }
        }
    }
}

// ---------------------------------------------------------------------------
extern "C" void kernel_launch(void* const* d_in, const int* in_sizes, int n_in,
                              void* d_out, int out_size, void* d_ws, size_t ws_size,
                              hipStream_t stream) {
    const void* X   = d_in[0];
    const void* msk = d_in[1];
    const void* Wq  = d_in[2];
    const void* bq  = d_in[3];
    const void* Wk  = d_in[4];
    const void* bk  = d_in[5];
    const void* Wv  = d_in[6];
    const void* bv  = d_in[7];

    char* ws = (char*)d_ws;
    float* kvredw = (float*)ws;                         // 48*4096*4 = 786 KB
    float* kspart = kvredw + 48 * 4096;                 // 0.75 MB
    float* vspart = kspart + 256 * 768;                 // 0.75 MB
    float* ksred  = vspart + 256 * 768;                 // 12 KB
    float* vsred  = ksred + 4 * 768;                    // 12 KB
    float* msumws = vsred + 4 * 768;                    // 16 B
    u32*   flagp  = (u32*)(msumws + 4);
    u16* qn = (u16*)(ws + (4 << 20));                   // 48 MB (bf16 Q-normed)
    u16* Wb = qn + (size_t)25165824;                    // 3.375 MB
    u16* Mb = Wb + (size_t)1769472;                     // 64 KB
    u16* Bb = Mb + (size_t)32768;                       // small

    u16*   Xb     = (u16*)d_out;                        // 48 MB bf16 X
    float* kvpart = (float*)((char*)d_out + 50331648);  // 50.3 MB fp32 partials
                                                        // (both dead before out_k writes)

    hipLaunchKernelGGL(sniff_k, dim3(1), dim3(256), 0, stream, X, flagp, msumws);
    hipLaunchKernelGGL(conv_k, dim3(13170), dim3(256), 0, stream,
                       X, Wq, Wk, Wv, bq, bk, bv, msk, flagp, Xb, Wb, Mb, Bb);
    hipLaunchKernelGGL(gemm_qkv_k, dim3(1536), dim3(512), 0, stream,
                       Xb, Wb, Bb, Mb, qn, kvpart, kspart, vspart, msumws);
    hipLaunchKernelGGL(kvred_k, dim3(49, 4), dim3(256), 0, stream,
                       kvpart, kvredw, kspart, vspart, ksred, vsred);
    hipLaunchKernelGGL(out_k, dim3(1536), dim3(256), 0, stream,
                       qn, kvredw, ksred, vsred, msumws, (float*)d_out);
}

// Round 4
// 399.381 us; speedup vs baseline: 1.4223x; 1.4223x over previous
//
#include <hip/hip_runtime.h>

// CosineSelfAttention  B=4, S=8192, HID=768, NH=12, HD=64, EPS=1e-5
// Round 10: revert to round-8 fused QKV GEMM (round-9 wide tiles collapsed
// occupancy to 1 block/CU -> 2x regression). Overlay ssbuf/colsum into one
// 2KB LDS buffer (+1 barrier): LDS 55296 -> 53248 B, just under the
// 160KiB/3 = 54613 threshold -> 3 blocks/CU (was 2). Everything else
// identical to round 8.

typedef unsigned short u16;
typedef unsigned int u32;

#define B_ 4
#define S_ 8192
#define HID_ 768
#define NH_ 12
#define HD_ 64
#define EPS_ 1e-5f

typedef __attribute__((ext_vector_type(8))) short bf16x8;
typedef __attribute__((ext_vector_type(4))) float f32x4;

__device__ __forceinline__ float bf2f(unsigned int u) {
    u <<= 16;
    return __builtin_bit_cast(float, u);
}
__device__ __forceinline__ u16 f2bf(float f) {
    u32 u = __builtin_bit_cast(u32, f);
    u = u + 0x7fffu + ((u >> 16) & 1u);   // round-to-nearest-even
    return (u16)(u >> 16);
}

#define ASYNC16(gptr, lptr)                                                        \
    __builtin_amdgcn_global_load_lds(                                              \
        (const __attribute__((address_space(1))) void*)(gptr),                     \
        (__attribute__((address_space(3))) void*)(lptr), 16, 0, 0)

// ---------------------------------------------------------------------------
// Kernel 0: dtype sniff (1 = fp32, 0 = bf16); also zero msumws.
// ---------------------------------------------------------------------------
__global__ void sniff_k(const void* __restrict__ X, u32* __restrict__ flag,
                        float* __restrict__ msumws)
{
    __shared__ int bad;
    if (threadIdx.x == 0) bad = 0;
    if (threadIdx.x < 4) msumws[threadIdx.x] = 0.f;
    __syncthreads();
    const u16* p = (const u16*)X;
    int loc = 0;
    for (int i = threadIdx.x; i < 8192; i += 256) {
        const u32 u = p[2 * i];
        const u32 e = (u >> 7) & 0xFFu;
        if (e >= 0xF8u) loc = 1;
    }
    if (loc) bad = 1;
    __syncthreads();
    if (threadIdx.x == 0) *flag = (u32)bad;
}

// ---------------------------------------------------------------------------
// Kernel 0b: convert X | Wq,Wk,Wv | mask | biases -> bf16 buffers.
// ---------------------------------------------------------------------------
__global__ __launch_bounds__(256) void conv_k(
    const void* __restrict__ X,
    const void* __restrict__ Wq, const void* __restrict__ Wk, const void* __restrict__ Wv,
    const void* __restrict__ bq, const void* __restrict__ bk, const void* __restrict__ bv,
    const void* __restrict__ mask,
    const u32* __restrict__ flagp,
    u16* __restrict__ Xb, u16* __restrict__ Wb, u16* __restrict__ Mb, u16* __restrict__ Bb)
{
    const int id = blockIdx.x;
    const void* src;
    u16* dst;
    int e;
    if (id < 12288) {                       // X
        src = X; dst = Xb; e = id * 2048 + threadIdx.x * 8;
    } else if (id < 13152) {                // W: 3 x 589824
        const int i = id - 12288;
        const int mat = i / 288;
        e = (i % 288) * 2048 + threadIdx.x * 8;
        src = (mat == 0) ? Wq : (mat == 1) ? Wk : Wv;
        dst = Wb + (size_t)mat * 589824;
    } else if (id < 13168) {                // mask: 32768
        const int i = id - 13152;
        src = mask; dst = Mb; e = i * 2048 + threadIdx.x * 8;
    } else {                                // biases: 3 x 768
        const int i = id - 13168;
        const int e0 = i * 2048 + threadIdx.x * 8;
        if (e0 >= 2304) return;
        const int mat = e0 / 768;
        src = (mat == 0) ? bq : (mat == 1) ? bk : bv;
        dst = Bb + mat * 768;
        e = e0 - mat * 768;
    }
    if (*flagp) {
        const float* s = (const float*)src + e;
        const float4 lo = *(const float4*)(s);
        const float4 hi = *(const float4*)(s + 4);
        uint4 o;
        o.x = (u32)f2bf(lo.x) | ((u32)f2bf(lo.y) << 16);
        o.y = (u32)f2bf(lo.z) | ((u32)f2bf(lo.w) << 16);
        o.z = (u32)f2bf(hi.x) | ((u32)f2bf(hi.y) << 16);
        o.w = (u32)f2bf(hi.z) | ((u32)f2bf(hi.w) << 16);
        *(uint4*)(dst + e) = o;
    } else {
        *(uint4*)(dst + e) = *(const uint4*)((const u16*)src + e);
    }
}

// ---------------------------------------------------------------------------
// Kernel 1: fused Q+K+V GEMM, one head per block (128 rows x 64 cols x 3 mats).
// 512 threads = 8 waves: wm = wid&3 (32-row chunk), wn = wid>>2 (32-col chunk).
// Epilogue: bias; Q,K mask+cosine-norm (cross-wave ss reduce); qn bf16 -> HBM;
// K/V transposed to LDS -> per-head khat^T.v 64x64 fp32 partial (determin.);
// fp32 colsum partials (kspart masked+normed K, vspart raw V); msum atomic.
// XCD swizzle: 12 head-blocks of a row-tile co-resident per XCD (A L2-hits).
// LDS: smem 51200 B + shbuf 2048 B (ssbuf/colsum overlay) = 53248 -> 3 blk/CU.
// ---------------------------------------------------------------------------
__global__ __launch_bounds__(512, 4) void gemm_qkv_k(
    const u16* __restrict__ Xb, const u16* __restrict__ Wb,
    const u16* __restrict__ Bb, const u16* __restrict__ Mb,
    u16* __restrict__ qn, float* __restrict__ kvpart,
    float* __restrict__ kspart, float* __restrict__ vspart,
    float* __restrict__ msumws)
{
    // staging: A[128][64] @0 (8192), BQ @8192, BK @12288, BV @16384 (4096 each)
    // epilogue: Ktrans[64][128] @0, Vtrans @8192, qn[128][72] @16384 (9216)
    __shared__ u16 smem[25600];
    __shared__ float shbuf[512];           // phase 1: ssbuf[2][2][128]
                                           // phase 2: colsum[2][4][64]
#define SSBUF(m, w, row) shbuf[((m) * 2 + (w)) * 128 + (row)]
#define COLSUM(m, w, c)  shbuf[((m) * 4 + (w)) * 64 + (c)]

    const int tid  = threadIdx.x;
    const int lane = tid & 63;
    const int wid  = tid >> 6;
    const int wm   = wid & 3;              // 32-row chunk
    const int wn   = wid >> 2;             // 32-col chunk

    const int bhw   = blockIdx.x;
    const int work  = (bhw & 7) * 384 + (bhw >> 3);   // XCD-contiguous
    const int row_t = work / 12;
    const int h     = work % 12;
    const int b     = row_t >> 6;
    const int rt_b  = row_t & 63;
    const int arow0 = row_t * 128;
    const int bcol0 = h * 64;
    const int bh    = b * NH_ + h;

    // ---- staging map: 40 chunks (A:16, BQ:8, BK:8, BV:8), 5 per wave
    const u16* src5[5];
    int loff5[5];
#pragma unroll
    for (int t = 0; t < 5; ++t) {
        const int cg = wid * 5 + t;
        int row;
        const u16* base;
        if (cg < 16) {
            row  = cg * 8 + (lane >> 3);
            base = Xb + (size_t)(arow0 + row) * HID_;
        } else {
            const int m = (cg - 16) >> 3;
            row  = ((cg - 16) & 7) * 8 + (lane >> 3);
            base = Wb + (size_t)m * 589824 + (size_t)(bcol0 + row) * HID_;
        }
        const int gseg = (lane & 7) ^ (row & 7);
        src5[t]  = base + gseg * 8;
        loff5[t] = cg * 512;
    }

    f32x4 acc[3][2][2];
#pragma unroll
    for (int m = 0; m < 3; ++m)
#pragma unroll
        for (int i = 0; i < 2; ++i)
#pragma unroll
            for (int j = 0; j < 2; ++j) acc[m][i][j] = (f32x4){0.f, 0.f, 0.f, 0.f};

    for (int k0 = 0; k0 < HID_; k0 += 64) {
#pragma unroll
        for (int t = 0; t < 5; ++t)
            ASYNC16(src5[t] + k0, smem + loff5[t]);
        __syncthreads();
#pragma unroll
        for (int ks = 0; ks < 2; ++ks) {
            const int phys = ((ks * 4 + (lane >> 4)) ^ (lane & 7)) * 8;
            bf16x8 af[2];
#pragma unroll
            for (int i = 0; i < 2; ++i)
                af[i] = *(const bf16x8*)(smem + (wm * 32 + i * 16 + (lane & 15)) * 64 + phys);
#pragma unroll
            for (int m = 0; m < 3; ++m)
#pragma unroll
                for (int j = 0; j < 2; ++j) {
                    const bf16x8 bf = *(const bf16x8*)(smem + 8192 + m * 4096 +
                                       (wn * 32 + j * 16 + (lane & 15)) * 64 + phys);
#pragma unroll
                    for (int i = 0; i < 2; ++i)
                        acc[m][i][j] = __builtin_amdgcn_mfma_f32_16x16x32_bf16(af[i], bf, acc[m][i][j], 0, 0, 0);
                }
        }
        __syncthreads();
    }

    // ---- bias
#pragma unroll
    for (int m = 0; m < 3; ++m)
#pragma unroll
        for (int j = 0; j < 2; ++j) {
            const float bs = bf2f(Bb[m * 768 + bcol0 + wn * 32 + j * 16 + (lane & 15)]);
#pragma unroll
            for (int i = 0; i < 2; ++i)
#pragma unroll
                for (int r = 0; r < 4; ++r) acc[m][i][j][r] += bs;
        }

    // ---- row sum-of-squares (Q,K) over this wave's 32 cols; cross-wave via LDS
#pragma unroll
    for (int m = 0; m < 2; ++m)
#pragma unroll
        for (int i = 0; i < 2; ++i)
#pragma unroll
            for (int r = 0; r < 4; ++r) {
                float ss = acc[m][i][0][r] * acc[m][i][0][r] +
                           acc[m][i][1][r] * acc[m][i][1][r];
#pragma unroll
                for (int off = 1; off < 16; off <<= 1) ss += __shfl_xor(ss, off, 64);
                if ((lane & 15) == 0)
                    SSBUF(m, wn, wm * 32 + i * 16 + (lane >> 4) * 4 + r) = ss;
            }
    __syncthreads();

    float scaleQ[2][4], scaleK[2][4];
#pragma unroll
    for (int i = 0; i < 2; ++i)
#pragma unroll
        for (int r = 0; r < 4; ++r) {
            const int row = wm * 32 + i * 16 + (lane >> 4) * 4 + r;
            const float mk = bf2f(Mb[arow0 + row]);
            const float mf = (mk == 0.f) ? 1.f : 0.f;
            const float ssq = SSBUF(0, 0, row) + SSBUF(0, 1, row);
            const float ssk = SSBUF(1, 0, row) + SSBUF(1, 1, row);
            scaleQ[i][r] = mf / (sqrtf(ssq) + EPS_);
            scaleK[i][r] = mf / (sqrtf(ssk) + EPS_);
        }
    __syncthreads();   // ssbuf reads done; shbuf reused as colsum below

    // ---- colsum partials (K scaled, V raw), per wave over its 32 rows
#pragma unroll
    for (int m = 0; m < 2; ++m)
#pragma unroll
        for (int j = 0; j < 2; ++j) {
            float s = 0.f;
#pragma unroll
            for (int i = 0; i < 2; ++i)
#pragma unroll
                for (int r = 0; r < 4; ++r)
                    s += (m == 0) ? acc[1][i][j][r] * scaleK[i][r] : acc[2][i][j][r];
            s += __shfl_xor(s, 16, 64);
            s += __shfl_xor(s, 32, 64);
            if (lane < 16) COLSUM(m, wm, wn * 32 + j * 16 + lane) = s;
        }

    // ---- scatter: Ktrans/Vtrans [64 d][128 s] (s-seg XOR-swz), qn [128][72]
#pragma unroll
    for (int i = 0; i < 2; ++i)
#pragma unroll
        for (int j = 0; j < 2; ++j) {
            const int d = wn * 32 + j * 16 + (lane & 15);
#pragma unroll
            for (int r = 0; r < 4; ++r) {
                const int srow = wm * 32 + i * 16 + (lane >> 4) * 4 + r;
                const int sadr = ((((srow >> 3) ^ (d & 7)) << 3) | (srow & 7));
                smem[d * 128 + sadr]        = f2bf(acc[1][i][j][r] * scaleK[i][r]);
                smem[8192 + d * 128 + sadr] = f2bf(acc[2][i][j][r]);
                smem[16384 + srow * 72 + d] = f2bf(acc[0][i][j][r] * scaleQ[i][r]);
            }
        }
    __syncthreads();

    // ---- kspart/vspart store
    if (tid < 128) {
        const int m = tid >> 6, c = tid & 63;
        const float s = COLSUM(m, 0, c) + COLSUM(m, 1, c) + COLSUM(m, 2, c) + COLSUM(m, 3, c);
        (m ? vspart : kspart)[row_t * 768 + bcol0 + c] = s;
    }

    // ---- msum (h==0 blocks only): exact integer-valued float atomics
    if (h == 0 && tid >= 128 && tid < 256) {
        float c = (bf2f(Mb[arow0 + (tid - 128)]) == 0.f) ? 1.f : 0.f;
#pragma unroll
        for (int off = 32; off > 0; off >>= 1) c += __shfl_down(c, off, 64);
        if (lane == 0) atomicAdd(&msumws[b], c);
    }

    // ---- kv partial: wave -> (D = wid&3, E pair = (wid>>2)*2 + e)
    {
        const int D  = wid & 3;
        const int E0 = (wid >> 2) * 2;
        f32x4 akv[2];
#pragma unroll
        for (int e = 0; e < 2; ++e) akv[e] = (f32x4){0.f, 0.f, 0.f, 0.f};
#pragma unroll
        for (int ks = 0; ks < 4; ++ks) {
            const int physs = ((ks * 4 + (lane >> 4)) ^ (lane & 7)) * 8;
            const bf16x8 ak = *(const bf16x8*)(smem + (D * 16 + (lane & 15)) * 128 + physs);
#pragma unroll
            for (int e = 0; e < 2; ++e) {
                const bf16x8 bv = *(const bf16x8*)(smem + 8192 + ((E0 + e) * 16 + (lane & 15)) * 128 + physs);
                akv[e] = __builtin_amdgcn_mfma_f32_16x16x32_bf16(ak, bv, akv[e], 0, 0, 0);
            }
        }
        float* dst = kvpart + ((size_t)bh * 64 + rt_b) * 4096;
#pragma unroll
        for (int e = 0; e < 2; ++e)
#pragma unroll
            for (int r = 0; r < 4; ++r)
                dst[(D * 16 + (lane >> 4) * 4 + r) * 64 + (E0 + e) * 16 + (lane & 15)] = akv[e][r];
    }

    // ---- qn store: 128x64 bf16 tile, coalesced from padded LDS
    {
        const int r  = tid >> 2;
        const int cb = (tid & 3) * 16;
        const uint4 w0 = *(const uint4*)(smem + 16384 + r * 72 + cb);
        const uint4 w1 = *(const uint4*)(smem + 16384 + r * 72 + cb + 8);
        u16* dstq = qn + (size_t)(arow0 + r) * HID_ + bcol0 + cb;
        *(uint4*)dstq = w0;
        *(uint4*)(dstq + 8) = w1;
    }
#undef SSBUF
#undef COLSUM
}

// ---------------------------------------------------------------------------
// Kernel 2: reduce kv partials (x<48) + ks/vs partials (x==48). grid (49,4).
// ---------------------------------------------------------------------------
__global__ __launch_bounds__(256) void kvred_k(
    const float* __restrict__ kvpart, float* __restrict__ kvredw,
    const float* __restrict__ kspart, const float* __restrict__ vspart,
    float* __restrict__ ksred, float* __restrict__ vsred)
{
    if (blockIdx.x < 48) {
        const int bhi  = blockIdx.x;
        const int base = blockIdx.y * 1024 + threadIdx.x * 4;
        const float* p = kvpart + (size_t)bhi * 64 * 4096 + base;
        f32x4 s = (f32x4){0.f, 0.f, 0.f, 0.f};
        for (int rt = 0; rt < 64; ++rt)
            s += *(const f32x4*)(p + (size_t)rt * 4096);
        *(f32x4*)(kvredw + (size_t)bhi * 4096 + base) = s;
    } else {
#pragma unroll
        for (int i = 0; i < 6; ++i) {
            const int idx = blockIdx.y * 1536 + i * 256 + threadIdx.x;   // 0..6143
            const int m = idx / 3072;
            const int rest = idx % 3072;
            const int bb = rest / 768;
            const int c  = rest % 768;
            const float* src = m ? vspart : kspart;
            float s = 0.f;
            for (int rt = 0; rt < 64; ++rt) s += src[(bb * 64 + rt) * 768 + c];
            (m ? vsred : ksred)[bb * 768 + c] = s;
        }
    }
}

// ---------------------------------------------------------------------------
// Kernel 3: out = (qn @ (kvH+kvL) + vsum) / (eps + msum + qn.ksum).
// ---------------------------------------------------------------------------
__global__ __launch_bounds__(256) void out_k(
    const u16* __restrict__ qn, const float* __restrict__ kvredw,
    const float* __restrict__ ksred, const float* __restrict__ vsred,
    const float* __restrict__ msumws, float* __restrict__ out)
{
    __shared__ u16 qs[128 * 128];          // [row][128] seg-swz by row&15
    __shared__ u16 ekvH[2 * 64 * 64];      // [hd][e][d swz]
    __shared__ u16 ekvL[2 * 64 * 64];
    __shared__ float ksl[128];
    __shared__ float vsl[128];
    __shared__ float dnl[256];

    const int tid  = threadIdx.x;
    const int lane = tid & 63;
    const int wid  = tid >> 6;
    const int wm   = wid >> 1, wn = wid & 1;

    const int bid   = blockIdx.x;
    const int row_t = bid / 6;
    const int ncol  = bid % 6;
    const int b     = row_t >> 6;
    const int arow0 = row_t * 128;
    const int bh0   = b * NH_ + ncol * 2;

    // stage qn tile (32 chunks, 8 per wave), seg pre-swizzled by row&15
#pragma unroll
    for (int t = 0; t < 8; ++t) {
        const int c   = wid * 8 + t;
        const int row = c * 4 + (lane >> 4);
        const int gseg = (lane & 15) ^ (row & 15);
        ASYNC16(qn + (size_t)(arow0 + row) * HID_ + ncol * 128 + gseg * 8,
                qs + c * 512);
    }

    // preload kv hi/lo split + ksum/vsum
    for (int it = 0; it < 32; ++it) {
        const int idx = it * 256 + tid;          // 8192 = 2 heads x 64d x 64e
        const int hd = idx >> 12;
        const int de = idx & 4095;
        const int d = de >> 6, e = de & 63;
        const float v = kvredw[(size_t)(bh0 + hd) * 4096 + de];
        const u16 hi = f2bf(v);
        const float rem = v - bf2f(hi);
        const int adr = hd * 4096 + e * 64 + ((((d >> 3) ^ (e & 7)) << 3) | (d & 7));
        ekvH[adr] = hi;
        ekvL[adr] = f2bf(rem);
    }
    if (tid < 128) {
        const int hd = tid >> 6, c = tid & 63;
        const int col = (ncol * 2 + hd) * 64 + c;
        ksl[tid] = ksred[b * 768 + col];
        vsl[tid] = vsred[b * 768 + col];
    }
    __syncthreads();

    // den = eps + msum + qn . ksum
    {
        const int row = tid & 127, hd2 = tid >> 7;
        float den = EPS_ + msumws[b];
#pragma unroll
        for (int c8 = 0; c8 < 8; ++c8) {
            const int colbase = hd2 * 64 + c8 * 8;
            const int phys = ((colbase >> 3) ^ (row & 15)) << 3;
            const bf16x8 qv = *(const bf16x8*)(qs + row * 128 + phys);
#pragma unroll
            for (int m = 0; m < 8; ++m)
                den += bf2f((u16)qv[m]) * ksl[colbase + m];
        }
        dnl[hd2 * 128 + row] = 1.f / den;
    }
    __syncthreads();

    // MFMA matvec: o = qn @ (kvH + kvL)   (head = wn)
    f32x4 o4[4][4];
#pragma unroll
    for (int i = 0; i < 4; ++i)
#pragma unroll
        for (int j = 0; j < 4; ++j) o4[i][j] = (f32x4){0.f, 0.f, 0.f, 0.f};
#pragma unroll
    for (int ks = 0; ks < 2; ++ks) {
        bf16x8 aq[4], bkH[4], bkL[4];
#pragma unroll
        for (int i = 0; i < 4; ++i) {
            const int row = wm * 64 + i * 16 + (lane & 15);
            const int colbase = wn * 64 + ks * 32 + (lane >> 4) * 8;
            const int phys = ((colbase >> 3) ^ (row & 15)) << 3;
            aq[i] = *(const bf16x8*)(qs + row * 128 + phys);
        }
#pragma unroll
        for (int j = 0; j < 4; ++j) {
            const int e = j * 16 + (lane & 15);
            const int physd = (((ks * 4 + (lane >> 4)) ^ (e & 7)) << 3);
            bkH[j] = *(const bf16x8*)(ekvH + wn * 4096 + e * 64 + physd);
            bkL[j] = *(const bf16x8*)(ekvL + wn * 4096 + e * 64 + physd);
        }
#pragma unroll
        for (int i = 0; i < 4; ++i)
#pragma unroll
            for (int j = 0; j < 4; ++j) {
                o4[i][j] = __builtin_amdgcn_mfma_f32_16x16x32_bf16(aq[i], bkH[j], o4[i][j], 0, 0, 0);
                o4[i][j] = __builtin_amdgcn_mfma_f32_16x16x32_bf16(aq[i], bkL[j], o4[i][j], 0, 0, 0);
            }
    }

    // + vsum, x 1/den, store fp32
#pragma unroll
    for (int i = 0; i < 4; ++i) {
#pragma unroll
        for (int r = 0; r < 4; ++r) {
            const int row = wm * 64 + i * 16 + (lane >> 4) * 4 + r;
            const float inv = dnl[wn * 128 + row];
            float* op = out + (size_t)(arow0 + row) * HID_ + ncol * 128 + wn * 64;
#pragma unroll
            for (int j = 0; j < 4; ++j) {
                const int e = j * 16 + (lane & 15);
                op[e] = (o4[i][j][r] + vsl[wn * 64 + e]) * inv;
            }
        }
    }
}

// ---------------------------------------------------------------------------
extern "C" void kernel_launch(void* const* d_in, const int* in_sizes, int n_in,
                              void* d_out, int out_size, void* d_ws, size_t ws_size,
                              hipStream_t stream) {
    const void* X   = d_in[0];
    const void* msk = d_in[1];
    const void* Wq  = d_in[2];
    const void* bq  = d_in[3];
    const void* Wk  = d_in[4];
    const void* bk  = d_in[5];
    const void* Wv  = d_in[6];
    const void* bv  = d_in[7];

    char* ws = (char*)d_ws;
    float* kvredw = (float*)ws;                         // 48*4096*4 = 786 KB
    float* kspart = kvredw + 48 * 4096;                 // 0.75 MB
    float* vspart = kspart + 256 * 768;                 // 0.75 MB
    float* ksred  = vspart + 256 * 768;                 // 12 KB
    float* vsred  = ksred + 4 * 768;                    // 12 KB
    float* msumws = vsred + 4 * 768;                    // 16 B
    u32*   flagp  = (u32*)(msumws + 4);
    u16* qn = (u16*)(ws + (4 << 20));                   // 48 MB (bf16 Q-normed)
    u16* Wb = qn + (size_t)25165824;                    // 3.375 MB
    u16* Mb = Wb + (size_t)1769472;                     // 64 KB
    u16* Bb = Mb + (size_t)32768;                       // small

    u16*   Xb     = (u16*)d_out;                        // 48 MB bf16 X
    float* kvpart = (float*)((char*)d_out + 50331648);  // 50.3 MB fp32 partials
                                                        // (both dead before out_k writes)

    hipLaunchKernelGGL(sniff_k, dim3(1), dim3(256), 0, stream, X, flagp, msumws);
    hipLaunchKernelGGL(conv_k, dim3(13170), dim3(256), 0, stream,
                       X, Wq, Wk, Wv, bq, bk, bv, msk, flagp, Xb, Wb, Mb, Bb);
    hipLaunchKernelGGL(gemm_qkv_k, dim3(3072), dim3(512), 0, stream,
                       Xb, Wb, Bb, Mb, qn, kvpart, kspart, vspart, msumws);
    hipLaunchKernelGGL(kvred_k, dim3(49, 4), dim3(256), 0, stream,
                       kvpart, kvredw, kspart, vspart, ksred, vsred);
    hipLaunchKernelGGL(out_k, dim3(1536), dim3(256), 0, stream,
                       qn, kvredw, ksred, vsred, msumws, (float*)d_out);
}

// Round 6
// 381.664 us; speedup vs baseline: 1.4883x; 1.0464x over previous
//
#include <hip/hip_runtime.h>

// CosineSelfAttention  B=4, S=8192, HID=768, NH=12, HD=64, EPS=1e-5
// Round 12: revert gemm_qkv_k to round-10 (round-11 dbuf overlapped buffers
// -> wrong results; one tile is 40960 B, not 20480). New: kvred_k computes
// the kv hi/lo bf16 split ONCE per (b,h) and writes pre-swizzled ekvHg/ekvLg;
// out_k stages them via global_load_lds with the qs tile (64 async chunks,
// one barrier) instead of 32 serial scattered-fp32-load+convert iterations
// per block. Bit-identical numerics.

typedef unsigned short u16;
typedef unsigned int u32;

#define B_ 4
#define S_ 8192
#define HID_ 768
#define NH_ 12
#define HD_ 64
#define EPS_ 1e-5f

typedef __attribute__((ext_vector_type(8))) short bf16x8;
typedef __attribute__((ext_vector_type(4))) float f32x4;

__device__ __forceinline__ float bf2f(unsigned int u) {
    u <<= 16;
    return __builtin_bit_cast(float, u);
}
__device__ __forceinline__ u16 f2bf(float f) {
    u32 u = __builtin_bit_cast(u32, f);
    u = u + 0x7fffu + ((u >> 16) & 1u);   // round-to-nearest-even
    return (u16)(u >> 16);
}

#define ASYNC16(gptr, lptr)                                                        \
    __builtin_amdgcn_global_load_lds(                                              \
        (const __attribute__((address_space(1))) void*)(gptr),                     \
        (__attribute__((address_space(3))) void*)(lptr), 16, 0, 0)

// ---------------------------------------------------------------------------
// Kernel 0: dtype sniff (1 = fp32, 0 = bf16); also zero msumws.
// ---------------------------------------------------------------------------
__global__ void sniff_k(const void* __restrict__ X, u32* __restrict__ flag,
                        float* __restrict__ msumws)
{
    __shared__ int bad;
    if (threadIdx.x == 0) bad = 0;
    if (threadIdx.x < 4) msumws[threadIdx.x] = 0.f;
    __syncthreads();
    const u16* p = (const u16*)X;
    int loc = 0;
    for (int i = threadIdx.x; i < 8192; i += 256) {
        const u32 u = p[2 * i];
        const u32 e = (u >> 7) & 0xFFu;
        if (e >= 0xF8u) loc = 1;
    }
    if (loc) bad = 1;
    __syncthreads();
    if (threadIdx.x == 0) *flag = (u32)bad;
}

// ---------------------------------------------------------------------------
// Kernel 0b: convert X | Wq,Wk,Wv | mask | biases -> bf16 buffers.
// ---------------------------------------------------------------------------
__global__ __launch_bounds__(256) void conv_k(
    const void* __restrict__ X,
    const void* __restrict__ Wq, const void* __restrict__ Wk, const void* __restrict__ Wv,
    const void* __restrict__ bq, const void* __restrict__ bk, const void* __restrict__ bv,
    const void* __restrict__ mask,
    const u32* __restrict__ flagp,
    u16* __restrict__ Xb, u16* __restrict__ Wb, u16* __restrict__ Mb, u16* __restrict__ Bb)
{
    const int id = blockIdx.x;
    const void* src;
    u16* dst;
    int e;
    if (id < 12288) {                       // X
        src = X; dst = Xb; e = id * 2048 + threadIdx.x * 8;
    } else if (id < 13152) {                // W: 3 x 589824
        const int i = id - 12288;
        const int mat = i / 288;
        e = (i % 288) * 2048 + threadIdx.x * 8;
        src = (mat == 0) ? Wq : (mat == 1) ? Wk : Wv;
        dst = Wb + (size_t)mat * 589824;
    } else if (id < 13168) {                // mask: 32768
        const int i = id - 13152;
        src = mask; dst = Mb; e = i * 2048 + threadIdx.x * 8;
    } else {                                // biases: 3 x 768
        const int i = id - 13168;
        const int e0 = i * 2048 + threadIdx.x * 8;
        if (e0 >= 2304) return;
        const int mat = e0 / 768;
        src = (mat == 0) ? bq : (mat == 1) ? bk : bv;
        dst = Bb + mat * 768;
        e = e0 - mat * 768;
    }
    if (*flagp) {
        const float* s = (const float*)src + e;
        const float4 lo = *(const float4*)(s);
        const float4 hi = *(const float4*)(s + 4);
        uint4 o;
        o.x = (u32)f2bf(lo.x) | ((u32)f2bf(lo.y) << 16);
        o.y = (u32)f2bf(lo.z) | ((u32)f2bf(lo.w) << 16);
        o.z = (u32)f2bf(hi.x) | ((u32)f2bf(hi.y) << 16);
        o.w = (u32)f2bf(hi.z) | ((u32)f2bf(hi.w) << 16);
        *(uint4*)(dst + e) = o;
    } else {
        *(uint4*)(dst + e) = *(const uint4*)((const u16*)src + e);
    }
}

// ---------------------------------------------------------------------------
// Kernel 1: fused Q+K+V GEMM, one head per block (128 rows x 64 cols x 3 mats).
// 512 threads = 8 waves: wm = wid&3 (32-row chunk), wn = wid>>2 (32-col chunk).
// (round-10 version: 1-phase K-loop, ssbuf/colsum overlay, 53248 B LDS)
// ---------------------------------------------------------------------------
__global__ __launch_bounds__(512, 4) void gemm_qkv_k(
    const u16* __restrict__ Xb, const u16* __restrict__ Wb,
    const u16* __restrict__ Bb, const u16* __restrict__ Mb,
    u16* __restrict__ qn, float* __restrict__ kvpart,
    float* __restrict__ kspart, float* __restrict__ vspart,
    float* __restrict__ msumws)
{
    // staging: A[128][64] @0 (8192), BQ @8192, BK @12288, BV @16384 (4096 each)
    // epilogue: Ktrans[64][128] @0, Vtrans @8192, qn[128][72] @16384 (9216)
    __shared__ u16 smem[25600];
    __shared__ float shbuf[512];           // phase 1: ssbuf[2][2][128]
                                           // phase 2: colsum[2][4][64]
#define SSBUF(m, w, row) shbuf[((m) * 2 + (w)) * 128 + (row)]
#define COLSUM(m, w, c)  shbuf[((m) * 4 + (w)) * 64 + (c)]

    const int tid  = threadIdx.x;
    const int lane = tid & 63;
    const int wid  = tid >> 6;
    const int wm   = wid & 3;              // 32-row chunk
    const int wn   = wid >> 2;             // 32-col chunk

    const int bhw   = blockIdx.x;
    const int work  = (bhw & 7) * 384 + (bhw >> 3);   // XCD-contiguous
    const int row_t = work / 12;
    const int h     = work % 12;
    const int b     = row_t >> 6;
    const int rt_b  = row_t & 63;
    const int arow0 = row_t * 128;
    const int bcol0 = h * 64;
    const int bh    = b * NH_ + h;

    // ---- staging map: 40 chunks (A:16, BQ:8, BK:8, BV:8), 5 per wave
    const u16* src5[5];
    int loff5[5];
#pragma unroll
    for (int t = 0; t < 5; ++t) {
        const int cg = wid * 5 + t;
        int row;
        const u16* base;
        if (cg < 16) {
            row  = cg * 8 + (lane >> 3);
            base = Xb + (size_t)(arow0 + row) * HID_;
        } else {
            const int m = (cg - 16) >> 3;
            row  = ((cg - 16) & 7) * 8 + (lane >> 3);
            base = Wb + (size_t)m * 589824 + (size_t)(bcol0 + row) * HID_;
        }
        const int gseg = (lane & 7) ^ (row & 7);
        src5[t]  = base + gseg * 8;
        loff5[t] = cg * 512;
    }

    f32x4 acc[3][2][2];
#pragma unroll
    for (int m = 0; m < 3; ++m)
#pragma unroll
        for (int i = 0; i < 2; ++i)
#pragma unroll
            for (int j = 0; j < 2; ++j) acc[m][i][j] = (f32x4){0.f, 0.f, 0.f, 0.f};

    for (int k0 = 0; k0 < HID_; k0 += 64) {
#pragma unroll
        for (int t = 0; t < 5; ++t)
            ASYNC16(src5[t] + k0, smem + loff5[t]);
        __syncthreads();
#pragma unroll
        for (int ks = 0; ks < 2; ++ks) {
            const int phys = ((ks * 4 + (lane >> 4)) ^ (lane & 7)) * 8;
            bf16x8 af[2];
#pragma unroll
            for (int i = 0; i < 2; ++i)
                af[i] = *(const bf16x8*)(smem + (wm * 32 + i * 16 + (lane & 15)) * 64 + phys);
#pragma unroll
            for (int m = 0; m < 3; ++m)
#pragma unroll
                for (int j = 0; j < 2; ++j) {
                    const bf16x8 bf = *(const bf16x8*)(smem + 8192 + m * 4096 +
                                       (wn * 32 + j * 16 + (lane & 15)) * 64 + phys);
#pragma unroll
                    for (int i = 0; i < 2; ++i)
                        acc[m][i][j] = __builtin_amdgcn_mfma_f32_16x16x32_bf16(af[i], bf, acc[m][i][j], 0, 0, 0);
                }
        }
        __syncthreads();
    }

    // ---- bias
#pragma unroll
    for (int m = 0; m < 3; ++m)
#pragma unroll
        for (int j = 0; j < 2; ++j) {
            const float bs = bf2f(Bb[m * 768 + bcol0 + wn * 32 + j * 16 + (lane & 15)]);
#pragma unroll
            for (int i = 0; i < 2; ++i)
#pragma unroll
                for (int r = 0; r < 4; ++r) acc[m][i][j][r] += bs;
        }

    // ---- row sum-of-squares (Q,K) over this wave's 32 cols; cross-wave via LDS
#pragma unroll
    for (int m = 0; m < 2; ++m)
#pragma unroll
        for (int i = 0; i < 2; ++i)
#pragma unroll
            for (int r = 0; r < 4; ++r) {
                float ss = acc[m][i][0][r] * acc[m][i][0][r] +
                           acc[m][i][1][r] * acc[m][i][1][r];
#pragma unroll
                for (int off = 1; off < 16; off <<= 1) ss += __shfl_xor(ss, off, 64);
                if ((lane & 15) == 0)
                    SSBUF(m, wn, wm * 32 + i * 16 + (lane >> 4) * 4 + r) = ss;
            }
    __syncthreads();

    float scaleQ[2][4], scaleK[2][4];
#pragma unroll
    for (int i = 0; i < 2; ++i)
#pragma unroll
        for (int r = 0; r < 4; ++r) {
            const int row = wm * 32 + i * 16 + (lane >> 4) * 4 + r;
            const float mk = bf2f(Mb[arow0 + row]);
            const float mf = (mk == 0.f) ? 1.f : 0.f;
            const float ssq = SSBUF(0, 0, row) + SSBUF(0, 1, row);
            const float ssk = SSBUF(1, 0, row) + SSBUF(1, 1, row);
            scaleQ[i][r] = mf / (sqrtf(ssq) + EPS_);
            scaleK[i][r] = mf / (sqrtf(ssk) + EPS_);
        }
    __syncthreads();   // ssbuf reads done; shbuf reused as colsum below

    // ---- colsum partials (K scaled, V raw), per wave over its 32 rows
#pragma unroll
    for (int m = 0; m < 2; ++m)
#pragma unroll
        for (int j = 0; j < 2; ++j) {
            float s = 0.f;
#pragma unroll
            for (int i = 0; i < 2; ++i)
#pragma unroll
                for (int r = 0; r < 4; ++r)
                    s += (m == 0) ? acc[1][i][j][r] * scaleK[i][r] : acc[2][i][j][r];
            s += __shfl_xor(s, 16, 64);
            s += __shfl_xor(s, 32, 64);
            if (lane < 16) COLSUM(m, wm, wn * 32 + j * 16 + lane) = s;
        }

    // ---- scatter: Ktrans/Vtrans [64 d][128 s] (s-seg XOR-swz), qn [128][72]
#pragma unroll
    for (int i = 0; i < 2; ++i)
#pragma unroll
        for (int j = 0; j < 2; ++j) {
            const int d = wn * 32 + j * 16 + (lane & 15);
#pragma unroll
            for (int r = 0; r < 4; ++r) {
                const int srow = wm * 32 + i * 16 + (lane >> 4) * 4 + r;
                const int sadr = ((((srow >> 3) ^ (d & 7)) << 3) | (srow & 7));
                smem[d * 128 + sadr]        = f2bf(acc[1][i][j][r] * scaleK[i][r]);
                smem[8192 + d * 128 + sadr] = f2bf(acc[2][i][j][r]);
                smem[16384 + srow * 72 + d] = f2bf(acc[0][i][j][r] * scaleQ[i][r]);
            }
        }
    __syncthreads();

    // ---- kspart/vspart store
    if (tid < 128) {
        const int m = tid >> 6, c = tid & 63;
        const float s = COLSUM(m, 0, c) + COLSUM(m, 1, c) + COLSUM(m, 2, c) + COLSUM(m, 3, c);
        (m ? vspart : kspart)[row_t * 768 + bcol0 + c] = s;
    }

    // ---- msum (h==0 blocks only): exact integer-valued float atomics
    if (h == 0 && tid >= 128 && tid < 256) {
        float c = (bf2f(Mb[arow0 + (tid - 128)]) == 0.f) ? 1.f : 0.f;
#pragma unroll
        for (int off = 32; off > 0; off >>= 1) c += __shfl_down(c, off, 64);
        if (lane == 0) atomicAdd(&msumws[b], c);
    }

    // ---- kv partial: wave -> (D = wid&3, E pair = (wid>>2)*2 + e)
    {
        const int D  = wid & 3;
        const int E0 = (wid >> 2) * 2;
        f32x4 akv[2];
#pragma unroll
        for (int e = 0; e < 2; ++e) akv[e] = (f32x4){0.f, 0.f, 0.f, 0.f};
#pragma unroll
        for (int ks = 0; ks < 4; ++ks) {
            const int physs = ((ks * 4 + (lane >> 4)) ^ (lane & 7)) * 8;
            const bf16x8 ak = *(const bf16x8*)(smem + (D * 16 + (lane & 15)) * 128 + physs);
#pragma unroll
            for (int e = 0; e < 2; ++e) {
                const bf16x8 bv = *(const bf16x8*)(smem + 8192 + ((E0 + e) * 16 + (lane & 15)) * 128 + physs);
                akv[e] = __builtin_amdgcn_mfma_f32_16x16x32_bf16(ak, bv, akv[e], 0, 0, 0);
            }
        }
        float* dst = kvpart + ((size_t)bh * 64 + rt_b) * 4096;
#pragma unroll
        for (int e = 0; e < 2; ++e)
#pragma unroll
            for (int r = 0; r < 4; ++r)
                dst[(D * 16 + (lane >> 4) * 4 + r) * 64 + (E0 + e) * 16 + (lane & 15)] = akv[e][r];
    }

    // ---- qn store: 128x64 bf16 tile, coalesced from padded LDS
    {
        const int r  = tid >> 2;
        const int cb = (tid & 3) * 16;
        const uint4 w0 = *(const uint4*)(smem + 16384 + r * 72 + cb);
        const uint4 w1 = *(const uint4*)(smem + 16384 + r * 72 + cb + 8);
        u16* dstq = qn + (size_t)(arow0 + r) * HID_ + bcol0 + cb;
        *(uint4*)dstq = w0;
        *(uint4*)(dstq + 8) = w1;
    }
#undef SSBUF
#undef COLSUM
}

// ---------------------------------------------------------------------------
// Kernel 2: reduce kv partials -> hi/lo bf16 split, PRE-SWIZZLED (x<48);
// reduce ks/vs partials (x==48). grid (49,4).
// ekv layout per (b,h): [e*64 + (((d>>3)^(e&7))<<3) | (d&7)] -- exactly the
// LDS layout out_k's matvec reads, so out_k can stage it linearly.
// ---------------------------------------------------------------------------
__global__ __launch_bounds__(256) void kvred_k(
    const float* __restrict__ kvpart,
    const float* __restrict__ kspart, const float* __restrict__ vspart,
    float* __restrict__ ksred, float* __restrict__ vsred,
    u16* __restrict__ ekvHg, u16* __restrict__ ekvLg)
{
    if (blockIdx.x < 48) {
        const int bhi  = blockIdx.x;
        const int base = blockIdx.y * 1024 + threadIdx.x * 4;   // de = d*64+e
        const float* p = kvpart + (size_t)bhi * 64 * 4096 + base;
        f32x4 s = (f32x4){0.f, 0.f, 0.f, 0.f};
        for (int rt = 0; rt < 64; ++rt)
            s += *(const f32x4*)(p + (size_t)rt * 4096);
        const int d  = base >> 6;
        const int e0 = base & 63;          // multiple of 4, no wrap
        u16* eh = ekvHg + (size_t)bhi * 4096;
        u16* el = ekvLg + (size_t)bhi * 4096;
#pragma unroll
        for (int q = 0; q < 4; ++q) {
            const int e = e0 + q;
            const float v = s[q];
            const u16 hi = f2bf(v);
            const float rem = v - bf2f(hi);
            const int adr = e * 64 + ((((d >> 3) ^ (e & 7)) << 3) | (d & 7));
            eh[adr] = hi;
            el[adr] = f2bf(rem);
        }
    } else {
#pragma unroll
        for (int i = 0; i < 6; ++i) {
            const int idx = blockIdx.y * 1536 + i * 256 + threadIdx.x;   // 0..6143
            const int m = idx / 3072;
            const int rest = idx % 3072;
            const int bb = rest / 768;
            const int c  = rest % 768;
            const float* src = m ? vspart : kspart;
            float s = 0.f;
            for (int rt = 0; rt < 64; ++rt) s += src[(bb * 64 + rt) * 768 + c];
            (m ? vsred : ksred)[bb * 768 + c] = s;
        }
    }
}

// ---------------------------------------------------------------------------
// Kernel 3: out = (qn @ (kvH+kvL) + vsum) / (eps + msum + qn.ksum).
// qs AND ekvH/ekvL staged via global_load_lds (64 chunks, one barrier).
// ---------------------------------------------------------------------------
__global__ __launch_bounds__(256) void out_k(
    const u16* __restrict__ qn, const float* __restrict__ ksred,
    const float* __restrict__ vsred, const float* __restrict__ msumws,
    const u16* __restrict__ ekvHg, const u16* __restrict__ ekvLg,
    float* __restrict__ out)
{
    __shared__ u16 qs[128 * 128];          // [row][128] seg-swz by row&15
    __shared__ u16 ekvH[2 * 64 * 64];      // [hd][e][d swz]  (pre-swizzled)
    __shared__ u16 ekvL[2 * 64 * 64];
    __shared__ float ksl[128];
    __shared__ float vsl[128];
    __shared__ float dnl[256];

    const int tid  = threadIdx.x;
    const int lane = tid & 63;
    const int wid  = tid >> 6;
    const int wm   = wid >> 1, wn = wid & 1;

    const int bid   = blockIdx.x;
    const int row_t = bid / 6;
    const int ncol  = bid % 6;
    const int b     = row_t >> 6;
    const int arow0 = row_t * 128;
    const int bh0   = b * NH_ + ncol * 2;

    // stage qn tile (32 chunks) + ekvH (16) + ekvL (16): 16 chunks per wave
#pragma unroll
    for (int t = 0; t < 16; ++t) {
        const int cg = wid * 16 + t;
        if (cg < 32) {
            const int row = cg * 4 + (lane >> 4);
            const int gseg = (lane & 15) ^ (row & 15);
            ASYNC16(qn + (size_t)(arow0 + row) * HID_ + ncol * 128 + gseg * 8,
                    qs + cg * 512);
        } else if (cg < 48) {
            const int c = cg - 32;
            ASYNC16(ekvHg + (size_t)bh0 * 4096 + c * 512 + lane * 8,
                    ekvH + c * 512);
        } else {
            const int c = cg - 48;
            ASYNC16(ekvLg + (size_t)bh0 * 4096 + c * 512 + lane * 8,
                    ekvL + c * 512);
        }
    }

    if (tid < 128) {
        const int hd = tid >> 6, c = tid & 63;
        const int col = (ncol * 2 + hd) * 64 + c;
        ksl[tid] = ksred[b * 768 + col];
        vsl[tid] = vsred[b * 768 + col];
    }
    __syncthreads();

    // den = eps + msum + qn . ksum
    {
        const int row = tid & 127, hd2 = tid >> 7;
        float den = EPS_ + msumws[b];
#pragma unroll
        for (int c8 = 0; c8 < 8; ++c8) {
            const int colbase = hd2 * 64 + c8 * 8;
            const int phys = ((colbase >> 3) ^ (row & 15)) << 3;
            const bf16x8 qv = *(const bf16x8*)(qs + row * 128 + phys);
#pragma unroll
            for (int m = 0; m < 8; ++m)
                den += bf2f((u16)qv[m]) * ksl[colbase + m];
        }
        dnl[hd2 * 128 + row] = 1.f / den;
    }
    __syncthreads();

    // MFMA matvec: o = qn @ (kvH + kvL)   (head = wn)
    f32x4 o4[4][4];
#pragma unroll
    for (int i = 0; i < 4; ++i)
#pragma unroll
        for (int j = 0; j < 4; ++j) o4[i][j] = (f32x4){0.f, 0.f, 0.f, 0.f};
#pragma unroll
    for (int ks = 0; ks < 2; ++ks) {
        bf16x8 aq[4], bkH[4], bkL[4];
#pragma unroll
        for (int i = 0; i < 4; ++i) {
            const int row = wm * 64 + i * 16 + (lane & 15);
            const int colbase = wn * 64 + ks * 32 + (lane >> 4) * 8;
            const int phys = ((colbase >> 3) ^ (row & 15)) << 3;
            aq[i] = *(const bf16x8*)(qs + row * 128 + phys);
        }
#pragma unroll
        for (int j = 0; j < 4; ++j) {
            const int e = j * 16 + (lane & 15);
            const int physd = (((ks * 4 + (lane >> 4)) ^ (e & 7)) << 3);
            bkH[j] = *(const bf16x8*)(ekvH + wn * 4096 + e * 64 + physd);
            bkL[j] = *(const bf16x8*)(ekvL + wn * 4096 + e * 64 + physd);
        }
#pragma unroll
        for (int i = 0; i < 4; ++i)
#pragma unroll
            for (int j = 0; j < 4; ++j) {
                o4[i][j] = __builtin_amdgcn_mfma_f32_16x16x32_bf16(aq[i], bkH[j], o4[i][j], 0, 0, 0);
                o4[i][j] = __builtin_amdgcn_mfma_f32_16x16x32_bf16(aq[i], bkL[j], o4[i][j], 0, 0, 0);
            }
    }

    // + vsum, x 1/den, store fp32
#pragma unroll
    for (int i = 0; i < 4; ++i) {
#pragma unroll
        for (int r = 0; r < 4; ++r) {
            const int row = wm * 64 + i * 16 + (lane >> 4) * 4 + r;
            const float inv = dnl[wn * 128 + row];
            float* op = out + (size_t)(arow0 + row) * HID_ + ncol * 128 + wn * 64;
#pragma unroll
            for (int j = 0; j < 4; ++j) {
                const int e = j * 16 + (lane & 15);
                op[e] = (o4[i][j][r] + vsl[wn * 64 + e]) * inv;
            }
        }
    }
}

// ---------------------------------------------------------------------------
extern "C" void kernel_launch(void* const* d_in, const int* in_sizes, int n_in,
                              void* d_out, int out_size, void* d_ws, size_t ws_size,
                              hipStream_t stream) {
    const void* X   = d_in[0];
    const void* msk = d_in[1];
    const void* Wq  = d_in[2];
    const void* bq  = d_in[3];
    const void* Wk  = d_in[4];
    const void* bk  = d_in[5];
    const void* Wv  = d_in[6];
    const void* bv  = d_in[7];

    char* ws = (char*)d_ws;
    float* kspart = (float*)ws;                         // 256*768*4 = 0.75 MB
    float* vspart = kspart + 256 * 768;                 // 0.75 MB
    float* ksred  = vspart + 256 * 768;                 // 12 KB
    float* vsred  = ksred + 4 * 768;                    // 12 KB
    u16*   ekvHg  = (u16*)(vsred + 4 * 768);            // 48*4096*2 = 384 KB
    u16*   ekvLg  = ekvHg + 48 * 4096;                  // 384 KB
    float* msumws = (float*)(ekvLg + 48 * 4096);        // 16 B
    u32*   flagp  = (u32*)(msumws + 4);
    u16* qn = (u16*)(ws + (4 << 20));                   // 48 MB (bf16 Q-normed)
    u16* Wb = qn + (size_t)25165824;                    // 3.375 MB
    u16* Mb = Wb + (size_t)1769472;                     // 64 KB
    u16* Bb = Mb + (size_t)32768;                       // small

    u16*   Xb     = (u16*)d_out;                        // 48 MB bf16 X
    float* kvpart = (float*)((char*)d_out + 50331648);  // 50.3 MB fp32 partials
                                                        // (both dead before out_k writes)

    hipLaunchKernelGGL(sniff_k, dim3(1), dim3(256), 0, stream, X, flagp, msumws);
    hipLaunchKernelGGL(conv_k, dim3(13170), dim3(256), 0, stream,
                       X, Wq, Wk, Wv, bq, bk, bv, msk, flagp, Xb, Wb, Mb, Bb);
    hipLaunchKernelGGL(gemm_qkv_k, dim3(3072), dim3(512), 0, stream,
                       Xb, Wb, Bb, Mb, qn, kvpart, kspart, vspart, msumws);
    hipLaunchKernelGGL(kvred_k, dim3(49, 4), dim3(256), 0, stream,
                       kvpart, kspart, vspart, ksred, vsred, ekvHg, ekvLg);
    hipLaunchKernelGGL(out_k, dim3(1536), dim3(256), 0, stream,
                       qn, ksred, vsred, msumws, ekvHg, ekvLg, (float*)d_out);
}